// Round 6
// baseline (445.267 us; speedup 1.0000x reference)
//
#include <hip/hip_runtime.h>
#include <math.h>

// Algebraic collapse: out depends on h = X@We + be only through h@Wc and h@Wf.
//   logits[:, 0:20]  = X @ (We@Wc) + (be@Wc + bc)
//   logits[:, 20:40] = X @ (We@Wf) + (be@Wf + bf)
// K0: zero Weff, fold bias2 = [be@Wc + bc | be@Wf + bf]
// K1: Weff = We @ [Wc|Wf]   (panel_gemm<4,false>, 4-way block-K atomic split)
// K2: out  = epilogue(X @ Weff + bias2)   (panel_gemm<16,true>)
//
// Round-6: rounds 3-5 all lost to per-thread state straddling the 128-VGPR
// granule (r3: SROA-defeat scratch; r4: 64+64 AGPR shuttle; r5: allocator
// pinned 128 under launch_bounds(512,2) and the scheduler serialized the
// pipeline to fit ~147 demand into it -> staging latency re-exposed, half
// the TLP, 144 us). Fix: make demand ~95 so the 128-reg tier holds with
// slack, and keep BOTH pipelining and TLP:
//  - R=4 rows/thread (4cg x 2rg, M-tile 8): acc2[5][5] v2f = 50 regs
//    (row 4 = zero pad so the reduce tree works on 48 = 16*3 values)
//  - 128-k supers: panel 20.8 KB, DOUBLE-buffered = 41.6 KB -> 2 blocks/CU
//    at 4 waves/SIMD (16 waves/CU): inter-block TLP on top of the pipeline
//  - pair-unrolled super loop: xa/xb and buffer selection fully static

typedef float v2f __attribute__((ext_vector_type(2)));
typedef float v4f __attribute__((ext_vector_type(4)));

#define KD    2048
#define NCLS  20
#define SMARG 0.31f

// ws layout (floats): Weff[2048*40] row-major, then bias2[40]
#define WEFF_OFF 0
#define BIAS_OFF 81920

#define PROW  260                   // 128-k paired panel row stride (256+4)
#define PANEL_FLOATS (20 * PROW)    // 5200 floats = 20.8 KB per buffer
#define HROW  164                   // Hacc row: 40 cols x 4 partials + 4 pad

static __device__ __forceinline__ v2f fma2(v2f a, v2f b, v2f c) {
#if __has_builtin(__builtin_elementwise_fma)
    return __builtin_elementwise_fma(a, b, c);   // -> v_pk_fma_f32
#else
    v2f r; r[0] = fmaf(a[0], b[0], c[0]); r[1] = fmaf(a[1], b[1], c[1]); return r;
#endif
}

// ---------------- K0: zero Weff, fold bias2 --------------------------------
__global__ __launch_bounds__(256)
void k0_prep(const float* __restrict__ Wc, const float* __restrict__ bc,
             const float* __restrict__ Wf, const float* __restrict__ bf,
             const float* __restrict__ be, float* __restrict__ ws)
{
    const int b = blockIdx.x;
    const int t = threadIdx.x;
    if (b < 80) {                                   // zero Weff: 80*256*4 = 81920
        v4f z = {0.f, 0.f, 0.f, 0.f};
        *(v4f*)&ws[WEFF_OFF + 4 * (b * 256 + t)] = z;
    } else {                                        // bias2[col], col = b-80
        const int col = b - 80;
        const float* Wp = (col < NCLS) ? Wc : Wf;
        const int cc = (col < NCLS) ? col : col - NCLS;
        float p = 0.f;
        for (int n = t; n < KD; n += 256)
            p = fmaf(be[n], Wp[n * NCLS + cc], p);
        __shared__ float red[256];
        red[t] = p;
        __syncthreads();
        for (int s = 128; s > 0; s >>= 1) {
            if (t < s) red[t] += red[t + s];
            __syncthreads();
        }
        if (t == 0)
            ws[BIAS_OFF + col] = red[0] + ((col < NCLS) ? bc[cc] : bf[cc]);
    }
}

// ---------------- panel GEMM: C[M,40] (+=) A[M,2048] @ B[2048,40] ----------
// Block: 512 thr = 8 waves = 4 col-groups(10 cols) x 2 row-groups(4 rows).
// Lanes span k (2 consecutive k/lane/super of 128 k). X read directly from
// global (coalesced, touched once, depth-2 reg pipeline). B staged per 128-k
// super into a double-buffered paired LDS panel [cj][2k] (stride 260), read
// as contiguous ds_read_b128 (conflict-free). acc2[5][5] v2f (row 4 = pad)
// -> v_pk_fma_f32, 24 MACs per ds_read_b128. End: 4-stage recursive-halving
// shfl reduce over 48 values (static GEPs only) -> LDS Hacc (4 k-partials)
// -> 8 row-lanes finalize.
template<int NSUP, bool FUSED>
__global__ __launch_bounds__(512, 4)
void panel_gemm(const float* __restrict__ A,
                const float* __restrict__ B0,
                const float* __restrict__ B1,
                float* __restrict__ Cacc,
                const float* __restrict__ bias2,
                float* __restrict__ outp)
{
    __shared__ __align__(16) float smem[2 * PANEL_FLOATS];
    const int tid  = threadIdx.x;
    const int lane = tid & 63;
    const int w    = tid >> 6;          // wave 0..7
    const int cg   = w & 3;             // col-group: cols [cg*10, cg*10+10)
    const int rg   = w >> 2;            // row-group: rows [rg*4, rg*4+4)

    int m0, kbase;
    if (FUSED) { m0 = blockIdx.x * 8;              kbase = 0; }
    else       { m0 = (int)(blockIdx.x >> 2) * 8;  kbase = (int)(blockIdx.x & 3) * 512; }

    const float* Arow = A + (size_t)(m0 + rg * 4) * KD + kbase + 2 * lane;

    // ---- helpers -----------------------------------------------------------
    // stage one 128-k super: 2560 col-pairs, 512 thr -> 5 v2f per thread
#define STAGE_LOAD(sv, kb)                                                     \
    {                                                                          \
        _Pragma("unroll")                                                      \
        for (int it = 0; it < 5; ++it) {                                       \
            const int pi = tid + it * 512;          /* < 2560 pairs */         \
            const int k = pi / 20, cj = pi % 20;                               \
            const float* bp;                                                   \
            unsigned soff;                                                     \
            if (FUSED)        { bp = B0; soff = (unsigned)((kb) + k) * 40 + 2 * cj; } \
            else if (cj < 10) { bp = B0; soff = (unsigned)((kb) + k) * 20 + 2 * cj; } \
            else              { bp = B1; soff = (unsigned)((kb) + k) * 20 + 2 * (cj - 10); } \
            sv[it] = *(const v2f*)(bp + soff);                                 \
        }                                                                      \
    }
#define STAGE_WRITE(sv, dst)                                                   \
    {                                                                          \
        _Pragma("unroll")                                                      \
        for (int it = 0; it < 5; ++it) {                                       \
            const int pi = tid + it * 512;                                     \
            const int k = pi / 20, cj = pi % 20;                               \
            *(v2f*)((dst) + cj * PROW + 2 * k) = sv[it];                       \
        }                                                                      \
    }
#define LOAD_X(xr, sup)                                                        \
    {                                                                          \
        _Pragma("unroll")                                                      \
        for (int r = 0; r < 4; ++r)                                            \
            xr[r] = *(const v2f*)(Arow + r * KD + (sup) * 128);                \
    }
#define COMPUTE(xr, base)                                                      \
    {                                                                          \
        const float* pb = (base) + cg * (5 * PROW) + 4 * lane;                 \
        _Pragma("unroll")                                                      \
        for (int j2 = 0; j2 < 5; ++j2) {                                       \
            v4f bv  = *(const v4f*)(pb + j2 * PROW);   /* contiguous b128 */   \
            v2f blo = {bv[0], bv[1]}, bhi = {bv[2], bv[3]};                    \
            _Pragma("unroll")                                                  \
            for (int r = 0; r < 4; ++r) {                                      \
                v2f x0 = {xr[r][0], xr[r][0]};                                 \
                v2f x1 = {xr[r][1], xr[r][1]};                                 \
                acc2[r][j2] = fma2(x1, bhi, fma2(x0, blo, acc2[r][j2]));       \
            }                                                                  \
        }                                                                      \
    }

    v2f acc2[5][5];                     // row 4 = zero pad for the reduce tree
    #pragma unroll
    for (int r = 0; r < 5; ++r)
        #pragma unroll
        for (int j = 0; j < 5; ++j) acc2[r][j] = (v2f){0.f, 0.f};

    v2f sv[5], xa[4], xb[4];

    // prologue: stage super 0 into buf0; X for supers 0,1
    STAGE_LOAD(sv, kbase);
    STAGE_WRITE(sv, smem);
    LOAD_X(xa, 0);
    LOAD_X(xb, 1);
    __syncthreads();

    // pair-unrolled super loop: even super -> buf0/xa, odd super -> buf1/xb
    #pragma unroll 1
    for (int sup = 0; sup < NSUP; sup += 2) {
        if (sup + 1 < NSUP)
            STAGE_LOAD(sv, kbase + (sup + 1) * 128);      // issue early
        COMPUTE(xa, smem);                                // buf0 (super sup)
        if (sup + 2 < NSUP) LOAD_X(xa, sup + 2);          // refill for t+2
        if (sup + 1 < NSUP) {
            STAGE_WRITE(sv, smem + PANEL_FLOATS);         // buf1 <- super sup+1
            __syncthreads();
            if (sup + 2 < NSUP)
                STAGE_LOAD(sv, kbase + (sup + 2) * 128);
            COMPUTE(xb, smem + PANEL_FLOATS);             // buf1 (super sup+1)
            if (sup + 3 < NSUP) LOAD_X(xb, sup + 3);
            if (sup + 2 < NSUP) {
                STAGE_WRITE(sv, smem);                    // buf0 <- super sup+2
                __syncthreads();
            }
        }
    }
#undef STAGE_LOAD
#undef STAGE_WRITE
#undef LOAD_X
#undef COMPUTE

    // ---- recursive-halving reduce-scatter over 16-lane groups -------------
    // 48 values/lane (40 real + 8 pad), flat i = r*10 + colInCg; ALL accesses
    // are compile-time-constant GEPs on acc2 (stays in VGPRs).
#define V(i) acc2[(i) / 10][((i) % 10) >> 1][(i) & 1]
    {
        const bool u1 = lane & 1;
        #pragma unroll
        for (int i = 0; i < 24; ++i) {
            float snd = u1 ? V(i) : V(i + 24);
            float rcv = __shfl_xor(snd, 1, 64);
            V(i) = (u1 ? V(i + 24) : V(i)) + rcv;
        }
        const bool u2 = lane & 2;
        #pragma unroll
        for (int i = 0; i < 12; ++i) {
            float snd = u2 ? V(i) : V(i + 12);
            float rcv = __shfl_xor(snd, 2, 64);
            V(i) = (u2 ? V(i + 12) : V(i)) + rcv;
        }
        const bool u4 = lane & 4;
        #pragma unroll
        for (int i = 0; i < 6; ++i) {
            float snd = u4 ? V(i) : V(i + 6);
            float rcv = __shfl_xor(snd, 4, 64);
            V(i) = (u4 ? V(i + 6) : V(i)) + rcv;
        }
        const bool u8 = lane & 8;
        #pragma unroll
        for (int i = 0; i < 3; ++i) {
            float snd = u8 ? V(i) : V(i + 3);
            float rcv = __shfl_xor(snd, 8, 64);
            V(i) = (u8 ? V(i + 3) : V(i)) + rcv;
        }
    }
    // lane holds flat indices base..base+2, base = 24a+12b+6c+3d (lane bits);
    // i >= 40 are pad sums (zero) and are discarded.
    {
        const int a = lane & 1, b = (lane >> 1) & 1;
        const int c = (lane >> 2) & 1, d = (lane >> 3) & 1;
        const int base = 24 * a + 12 * b + 6 * c + 3 * d;
        const int g    = lane >> 4;                 // k-partial group 0..3
        #pragma unroll
        for (int t = 0; t < 3; ++t) {
            const int i = base + t;
            if (i < 40) {
                const int row = i / 10, col = i % 10;
                smem[(rg * 4 + row) * HROW + (cg * 10 + col) * 4 + g] = V(t);
            }
        }
    }
#undef V
    __syncthreads();

    if (tid < 8) {
        float l[40];
        #pragma unroll
        for (int cc = 0; cc < 40; ++cc) {
            v4f q = *(const v4f*)(smem + tid * HROW + cc * 4);
            l[cc] = (q[0] + q[1]) + (q[2] + q[3]);
        }
        if (FUSED) {
            #pragma unroll
            for (int cc = 0; cc < 40; ++cc) l[cc] += bias2[cc];
            float mC = l[0];
            #pragma unroll
            for (int cc = 1; cc < 20; ++cc) mC = fmaxf(mC, l[cc]);
            float e[20];
            float sC = 0.f;
            #pragma unroll
            for (int cc = 0; cc < 20; ++cc) { e[cc] = expf(l[cc] - mC); sC += e[cc]; }
            float mF = l[20], mnF = l[20];
            #pragma unroll
            for (int cc = 21; cc < 40; ++cc) {
                mF = fmaxf(mF, l[cc]);
                mnF = fminf(mnF, l[cc]);
            }
            float sF = 0.f;
            #pragma unroll
            for (int cc = 20; cc < 40; ++cc) sF += expf(l[cc] - mF);
            float pred  = 1.f / sC;                 // max softmax == exp(0)/sum
            float tau   = expf(mnF - mF) / sF;      // min softmax of flow head
            float scale = (pred >= tau + SMARG) ? pred : 0.f;
            float* op = outp + (size_t)(m0 + tid) * NCLS;
            #pragma unroll
            for (int j = 0; j < 5; ++j) {
                v4f o;
                #pragma unroll
                for (int i = 0; i < 4; ++i) o[i] = e[4 * j + i] * scale;
                *(v4f*)(op + 4 * j) = o;
            }
        } else {
            #pragma unroll
            for (int cc = 0; cc < 40; ++cc)
                atomicAdd(Cacc + (size_t)(m0 + tid) * 40 + cc, l[cc]);
        }
    }
}

extern "C" void kernel_launch(void* const* d_in, const int* in_sizes, int n_in,
                              void* d_out, int out_size, void* d_ws, size_t ws_size,
                              hipStream_t stream) {
    const float* X  = (const float*)d_in[0];
    const float* We = (const float*)d_in[1];
    const float* be = (const float*)d_in[2];
    const float* Wc = (const float*)d_in[3];
    const float* bc = (const float*)d_in[4];
    const float* Wf = (const float*)d_in[5];
    const float* bf = (const float*)d_in[6];
    float* out = (float*)d_out;
    float* ws  = (float*)d_ws;
    (void)in_sizes; (void)n_in; (void)out_size; (void)ws_size;

    // K0: zero Weff + fold bias2
    k0_prep<<<dim3(120), dim3(256), 0, stream>>>(Wc, bc, Wf, bf, be, ws);
    // K1: Weff = We @ [Wc|Wf]  (256 row-blocks x 4 block-K splits = 1024 blocks)
    panel_gemm<4, false><<<dim3(1024), dim3(512), 0, stream>>>(
        We, Wc, Wf, ws + WEFF_OFF, nullptr, nullptr);
    // K2: out = softmax-threshold(X @ Weff + bias2)  (2048 blocks x 8 rows)
    panel_gemm<16, true><<<dim3(2048), dim3(512), 0, stream>>>(
        X, ws + WEFF_OFF, nullptr, nullptr, ws + BIAS_OFF, out);
}

// Round 7
// 366.253 us; speedup vs baseline: 1.2157x; 1.2157x over previous
//
#include <hip/hip_runtime.h>
#include <math.h>

// Algebraic collapse: out depends on h = X@We + be only through h@Wc and h@Wf.
//   logits[:, 0:20]  = X @ (We@Wc) + (be@Wc + bc)
//   logits[:, 20:40] = X @ (We@Wf) + (be@Wf + bf)
// K0: zero Weff, fold bias2 = [be@Wc + bc | be@Wf + bf]
// K1: Weff = We @ [Wc|Wf]   (panel_gemm<4,false>, 4-way block-K atomic split)
// K2: out  = epilogue(X @ Weff + bias2)   (panel_gemm<16,true>)
//
// Round-7: EMPIRICAL launch_bounds finding (rounds 3-6): hipcc's second
// __launch_bounds__ arg behaves as CUDA-style MIN BLOCKS PER CU, not
// min-waves-per-EU: (512,4) -> 32 waves/CU -> 64-reg cap (observed
// VGPR_Count=64 + spill in r4/r6); (512,2) -> 16 waves/CU -> 128-reg cap
// (observed 128 in r3/r5). Round 6 sized per-thread state to ~95 regs for
// a 128 cap but requested (512,4) = a 64 cap -> 107 MB scratch spill.
// This round: IDENTICAL kernel with __launch_bounds__(512, 2): demand ~95
// fits the 128-reg tier with slack -> no spill, no AGPR shuttle, still
// 2 blocks/CU (LDS 42 KB) = 16 waves/CU TLP on top of the pipeline:
//  - R=4 rows/thread (4cg x 2rg, M-tile 8): acc2[5][5] v2f = 50 regs
//    (row 4 = zero pad so the reduce tree works on 48 = 16*3 values)
//  - 128-k supers: panel 20.8 KB, double-buffered; B global loads issued
//    BEFORE compute, ds_writes AFTER (T14 split) -> staging latency hidden
//  - X depth-2 reg pipeline (xa/xb, refill for t+2 right after last use)

typedef float v2f __attribute__((ext_vector_type(2)));
typedef float v4f __attribute__((ext_vector_type(4)));

#define KD    2048
#define NCLS  20
#define SMARG 0.31f

// ws layout (floats): Weff[2048*40] row-major, then bias2[40]
#define WEFF_OFF 0
#define BIAS_OFF 81920

#define PROW  260                   // 128-k paired panel row stride (256+4)
#define PANEL_FLOATS (20 * PROW)    // 5200 floats = 20.8 KB per buffer
#define HROW  164                   // Hacc row: 40 cols x 4 partials + 4 pad

static __device__ __forceinline__ v2f fma2(v2f a, v2f b, v2f c) {
#if __has_builtin(__builtin_elementwise_fma)
    return __builtin_elementwise_fma(a, b, c);   // -> v_pk_fma_f32
#else
    v2f r; r[0] = fmaf(a[0], b[0], c[0]); r[1] = fmaf(a[1], b[1], c[1]); return r;
#endif
}

// ---------------- K0: zero Weff, fold bias2 --------------------------------
__global__ __launch_bounds__(256)
void k0_prep(const float* __restrict__ Wc, const float* __restrict__ bc,
             const float* __restrict__ Wf, const float* __restrict__ bf,
             const float* __restrict__ be, float* __restrict__ ws)
{
    const int b = blockIdx.x;
    const int t = threadIdx.x;
    if (b < 80) {                                   // zero Weff: 80*256*4 = 81920
        v4f z = {0.f, 0.f, 0.f, 0.f};
        *(v4f*)&ws[WEFF_OFF + 4 * (b * 256 + t)] = z;
    } else {                                        // bias2[col], col = b-80
        const int col = b - 80;
        const float* Wp = (col < NCLS) ? Wc : Wf;
        const int cc = (col < NCLS) ? col : col - NCLS;
        float p = 0.f;
        for (int n = t; n < KD; n += 256)
            p = fmaf(be[n], Wp[n * NCLS + cc], p);
        __shared__ float red[256];
        red[t] = p;
        __syncthreads();
        for (int s = 128; s > 0; s >>= 1) {
            if (t < s) red[t] += red[t + s];
            __syncthreads();
        }
        if (t == 0)
            ws[BIAS_OFF + col] = red[0] + ((col < NCLS) ? bc[cc] : bf[cc]);
    }
}

// ---------------- panel GEMM: C[M,40] (+=) A[M,2048] @ B[2048,40] ----------
// Block: 512 thr = 8 waves = 4 col-groups(10 cols) x 2 row-groups(4 rows).
// Lanes span k (2 consecutive k/lane/super of 128 k). X read directly from
// global (coalesced, touched once, depth-2 reg pipeline). B staged per 128-k
// super into a double-buffered paired LDS panel [cj][2k] (stride 260), read
// as contiguous ds_read_b128 (conflict-free). acc2[5][5] v2f (row 4 = pad)
// -> v_pk_fma_f32, 24 MACs per ds_read_b128. End: 4-stage recursive-halving
// shfl reduce over 48 values (static GEPs only) -> LDS Hacc (4 k-partials)
// -> 8 row-lanes finalize.
template<int NSUP, bool FUSED>
__global__ __launch_bounds__(512, 2)
void panel_gemm(const float* __restrict__ A,
                const float* __restrict__ B0,
                const float* __restrict__ B1,
                float* __restrict__ Cacc,
                const float* __restrict__ bias2,
                float* __restrict__ outp)
{
    __shared__ __align__(16) float smem[2 * PANEL_FLOATS];
    const int tid  = threadIdx.x;
    const int lane = tid & 63;
    const int w    = tid >> 6;          // wave 0..7
    const int cg   = w & 3;             // col-group: cols [cg*10, cg*10+10)
    const int rg   = w >> 2;            // row-group: rows [rg*4, rg*4+4)

    int m0, kbase;
    if (FUSED) { m0 = blockIdx.x * 8;              kbase = 0; }
    else       { m0 = (int)(blockIdx.x >> 2) * 8;  kbase = (int)(blockIdx.x & 3) * 512; }

    const float* Arow = A + (size_t)(m0 + rg * 4) * KD + kbase + 2 * lane;

    // ---- helpers -----------------------------------------------------------
    // stage one 128-k super: 2560 col-pairs, 512 thr -> 5 v2f per thread
#define STAGE_LOAD(sv, kb)                                                     \
    {                                                                          \
        _Pragma("unroll")                                                      \
        for (int it = 0; it < 5; ++it) {                                       \
            const int pi = tid + it * 512;          /* < 2560 pairs */         \
            const int k = pi / 20, cj = pi % 20;                               \
            const float* bp;                                                   \
            unsigned soff;                                                     \
            if (FUSED)        { bp = B0; soff = (unsigned)((kb) + k) * 40 + 2 * cj; } \
            else if (cj < 10) { bp = B0; soff = (unsigned)((kb) + k) * 20 + 2 * cj; } \
            else              { bp = B1; soff = (unsigned)((kb) + k) * 20 + 2 * (cj - 10); } \
            sv[it] = *(const v2f*)(bp + soff);                                 \
        }                                                                      \
    }
#define STAGE_WRITE(sv, dst)                                                   \
    {                                                                          \
        _Pragma("unroll")                                                      \
        for (int it = 0; it < 5; ++it) {                                       \
            const int pi = tid + it * 512;                                     \
            const int k = pi / 20, cj = pi % 20;                               \
            *(v2f*)((dst) + cj * PROW + 2 * k) = sv[it];                       \
        }                                                                      \
    }
#define LOAD_X(xr, sup)                                                        \
    {                                                                          \
        _Pragma("unroll")                                                      \
        for (int r = 0; r < 4; ++r)                                            \
            xr[r] = *(const v2f*)(Arow + r * KD + (sup) * 128);                \
    }
#define COMPUTE(xr, base)                                                      \
    {                                                                          \
        const float* pb = (base) + cg * (5 * PROW) + 4 * lane;                 \
        _Pragma("unroll")                                                      \
        for (int j2 = 0; j2 < 5; ++j2) {                                       \
            v4f bv  = *(const v4f*)(pb + j2 * PROW);   /* contiguous b128 */   \
            v2f blo = {bv[0], bv[1]}, bhi = {bv[2], bv[3]};                    \
            _Pragma("unroll")                                                  \
            for (int r = 0; r < 4; ++r) {                                      \
                v2f x0 = {xr[r][0], xr[r][0]};                                 \
                v2f x1 = {xr[r][1], xr[r][1]};                                 \
                acc2[r][j2] = fma2(x1, bhi, fma2(x0, blo, acc2[r][j2]));       \
            }                                                                  \
        }                                                                      \
    }

    v2f acc2[5][5];                     // row 4 = zero pad for the reduce tree
    #pragma unroll
    for (int r = 0; r < 5; ++r)
        #pragma unroll
        for (int j = 0; j < 5; ++j) acc2[r][j] = (v2f){0.f, 0.f};

    v2f sv[5], xa[4], xb[4];

    // prologue: stage super 0 into buf0; X for supers 0,1
    STAGE_LOAD(sv, kbase);
    STAGE_WRITE(sv, smem);
    LOAD_X(xa, 0);
    LOAD_X(xb, 1);
    __syncthreads();

    // pair-unrolled super loop: even super -> buf0/xa, odd super -> buf1/xb
    #pragma unroll 1
    for (int sup = 0; sup < NSUP; sup += 2) {
        if (sup + 1 < NSUP)
            STAGE_LOAD(sv, kbase + (sup + 1) * 128);      // issue early
        COMPUTE(xa, smem);                                // buf0 (super sup)
        if (sup + 2 < NSUP) LOAD_X(xa, sup + 2);          // refill for t+2
        if (sup + 1 < NSUP) {
            STAGE_WRITE(sv, smem + PANEL_FLOATS);         // buf1 <- super sup+1
            __syncthreads();
            if (sup + 2 < NSUP)
                STAGE_LOAD(sv, kbase + (sup + 2) * 128);
            COMPUTE(xb, smem + PANEL_FLOATS);             // buf1 (super sup+1)
            if (sup + 3 < NSUP) LOAD_X(xb, sup + 3);
            if (sup + 2 < NSUP) {
                STAGE_WRITE(sv, smem);                    // buf0 <- super sup+2
                __syncthreads();
            }
        }
    }
#undef STAGE_LOAD
#undef STAGE_WRITE
#undef LOAD_X
#undef COMPUTE

    // ---- recursive-halving reduce-scatter over 16-lane groups -------------
    // 48 values/lane (40 real + 8 pad), flat i = r*10 + colInCg; ALL accesses
    // are compile-time-constant GEPs on acc2 (stays in VGPRs).
#define V(i) acc2[(i) / 10][((i) % 10) >> 1][(i) & 1]
    {
        const bool u1 = lane & 1;
        #pragma unroll
        for (int i = 0; i < 24; ++i) {
            float snd = u1 ? V(i) : V(i + 24);
            float rcv = __shfl_xor(snd, 1, 64);
            V(i) = (u1 ? V(i + 24) : V(i)) + rcv;
        }
        const bool u2 = lane & 2;
        #pragma unroll
        for (int i = 0; i < 12; ++i) {
            float snd = u2 ? V(i) : V(i + 12);
            float rcv = __shfl_xor(snd, 2, 64);
            V(i) = (u2 ? V(i + 12) : V(i)) + rcv;
        }
        const bool u4 = lane & 4;
        #pragma unroll
        for (int i = 0; i < 6; ++i) {
            float snd = u4 ? V(i) : V(i + 6);
            float rcv = __shfl_xor(snd, 4, 64);
            V(i) = (u4 ? V(i + 6) : V(i)) + rcv;
        }
        const bool u8 = lane & 8;
        #pragma unroll
        for (int i = 0; i < 3; ++i) {
            float snd = u8 ? V(i) : V(i + 3);
            float rcv = __shfl_xor(snd, 8, 64);
            V(i) = (u8 ? V(i + 3) : V(i)) + rcv;
        }
    }
    // lane holds flat indices base..base+2, base = 24a+12b+6c+3d (lane bits);
    // i >= 40 are pad sums (zero) and are discarded.
    {
        const int a = lane & 1, b = (lane >> 1) & 1;
        const int c = (lane >> 2) & 1, d = (lane >> 3) & 1;
        const int base = 24 * a + 12 * b + 6 * c + 3 * d;
        const int g    = lane >> 4;                 // k-partial group 0..3
        #pragma unroll
        for (int t = 0; t < 3; ++t) {
            const int i = base + t;
            if (i < 40) {
                const int row = i / 10, col = i % 10;
                smem[(rg * 4 + row) * HROW + (cg * 10 + col) * 4 + g] = V(t);
            }
        }
    }
#undef V
    __syncthreads();

    if (tid < 8) {
        float l[40];
        #pragma unroll
        for (int cc = 0; cc < 40; ++cc) {
            v4f q = *(const v4f*)(smem + tid * HROW + cc * 4);
            l[cc] = (q[0] + q[1]) + (q[2] + q[3]);
        }
        if (FUSED) {
            #pragma unroll
            for (int cc = 0; cc < 40; ++cc) l[cc] += bias2[cc];
            float mC = l[0];
            #pragma unroll
            for (int cc = 1; cc < 20; ++cc) mC = fmaxf(mC, l[cc]);
            float e[20];
            float sC = 0.f;
            #pragma unroll
            for (int cc = 0; cc < 20; ++cc) { e[cc] = expf(l[cc] - mC); sC += e[cc]; }
            float mF = l[20], mnF = l[20];
            #pragma unroll
            for (int cc = 21; cc < 40; ++cc) {
                mF = fmaxf(mF, l[cc]);
                mnF = fminf(mnF, l[cc]);
            }
            float sF = 0.f;
            #pragma unroll
            for (int cc = 20; cc < 40; ++cc) sF += expf(l[cc] - mF);
            float pred  = 1.f / sC;                 // max softmax == exp(0)/sum
            float tau   = expf(mnF - mF) / sF;      // min softmax of flow head
            float scale = (pred >= tau + SMARG) ? pred : 0.f;
            float* op = outp + (size_t)(m0 + tid) * NCLS;
            #pragma unroll
            for (int j = 0; j < 5; ++j) {
                v4f o;
                #pragma unroll
                for (int i = 0; i < 4; ++i) o[i] = e[4 * j + i] * scale;
                *(v4f*)(op + 4 * j) = o;
            }
        } else {
            #pragma unroll
            for (int cc = 0; cc < 40; ++cc)
                atomicAdd(Cacc + (size_t)(m0 + tid) * 40 + cc, l[cc]);
        }
    }
}

extern "C" void kernel_launch(void* const* d_in, const int* in_sizes, int n_in,
                              void* d_out, int out_size, void* d_ws, size_t ws_size,
                              hipStream_t stream) {
    const float* X  = (const float*)d_in[0];
    const float* We = (const float*)d_in[1];
    const float* be = (const float*)d_in[2];
    const float* Wc = (const float*)d_in[3];
    const float* bc = (const float*)d_in[4];
    const float* Wf = (const float*)d_in[5];
    const float* bf = (const float*)d_in[6];
    float* out = (float*)d_out;
    float* ws  = (float*)d_ws;
    (void)in_sizes; (void)n_in; (void)out_size; (void)ws_size;

    // K0: zero Weff + fold bias2
    k0_prep<<<dim3(120), dim3(256), 0, stream>>>(Wc, bc, Wf, bf, be, ws);
    // K1: Weff = We @ [Wc|Wf]  (256 row-blocks x 4 block-K splits = 1024 blocks)
    panel_gemm<4, false><<<dim3(1024), dim3(512), 0, stream>>>(
        We, Wc, Wf, ws + WEFF_OFF, nullptr, nullptr);
    // K2: out = softmax-threshold(X @ Weff + bias2)  (2048 blocks x 8 rows)
    panel_gemm<16, true><<<dim3(2048), dim3(512), 0, stream>>>(
        X, ws + WEFF_OFF, nullptr, nullptr, ws + BIAS_OFF, out);
}

// Round 8
// 243.473 us; speedup vs baseline: 1.8288x; 1.5043x over previous
//
#include <hip/hip_runtime.h>
#include <math.h>

// Algebraic collapse: out depends on h = X@We + be only through h@Wc and h@Wf.
//   logits[:, 0:20]  = X @ (We@Wc) + (be@Wc + bc)
//   logits[:, 20:40] = X @ (We@Wf) + (be@Wf + bf)
// K0: pack Wcat=[Wc|Wf], zero Weff, fold bias2 = be@Wcat + [bc|bf]
// K1: Weff = We @ Wcat        (skinny GEMM template, atomic split-K)
// K2: out  = epilogue(X @ Weff + bias2)   (fused softmax+threshold)
//
// Round-8: rounds 2-7's lanes-span-k/LDS-panel designs were all latency-bound
// by construction (barrier-locked staging, 110-494 us). The round-0 structure
// (lanes span rows, B wave-uniform via s_load -> zero per-lane B cost) is the
// best measured (K2 ~60 us). This round = round-0 kernel VERBATIM with ONE
// change: packed inner-loop math (acc[20] -> v2f accv[10], v_pk_fma_f32 with
// s_load_dwordx2 B operand) -- halves VALU issue AND SMEM instruction count.
// Hacc writeback stays scalar (HACC_STR=41 odd -> v2f store would be
// misaligned); LDS layout + epilogue byte-identical to round 0.

typedef float v2f __attribute__((ext_vector_type(2)));

#define KD    2048
#define NROWS 16384
#define NCLS  20
#define NC2   40
#define SMARG 0.31f

// ws layout (floats): total 163,880 floats = 656 KB
#define WCAT_OFF 0
#define WEFF_OFF 81920
#define BIAS_OFF 163840

#define XS_STR  65            // Xs[k][row], 65 mod 32 = 1 -> conflict-free
#define XS_BUF  (64 * XS_STR) // 4160 floats per buffer
#define HACC_STR 41           // Hacc[ks][row][c], 41 odd -> conflict-free
#define HACC_WS  (64 * HACC_STR)
#define SMEM_FLOATS (8 * HACC_WS)   // 20992 > 2*XS_BUF(8320); union of Xs-dbuf / Hacc

static __device__ __forceinline__ v2f fma2(v2f a, v2f b, v2f c) {
#if __has_builtin(__builtin_elementwise_fma)
    return __builtin_elementwise_fma(a, b, c);   // -> v_pk_fma_f32
#else
    v2f r; r[0] = fmaf(a[0], b[0], c[0]); r[1] = fmaf(a[1], b[1], c[1]); return r;
#endif
}

// ---------------- K0: pack Wcat, zero Weff, fold bias2 ----------------------
__global__ __launch_bounds__(256)
void k0_prep(const float* __restrict__ Wc, const float* __restrict__ bc,
             const float* __restrict__ Wf, const float* __restrict__ bf,
             const float* __restrict__ be, float* __restrict__ ws)
{
    const int b = blockIdx.x;
    const int t = threadIdx.x;
    if (b < 320) {
        const int idx = b * 256 + t;                 // 0..81919
        const int n = idx / NC2, c = idx % NC2;
        ws[WCAT_OFF + idx] = (c < NCLS) ? Wc[n * NCLS + c] : Wf[n * NCLS + (c - NCLS)];
        ws[WEFF_OFF + idx] = 0.f;                    // ws re-poisoned each call
    } else {
        const int col = b - 320;                     // 0..39
        const float* Wp = (col < NCLS) ? Wc : Wf;
        const int cc = (col < NCLS) ? col : col - NCLS;
        float p = 0.f;
        for (int n = t; n < KD; n += 256)
            p = fmaf(be[n], Wp[n * NCLS + cc], p);
        __shared__ float red[256];
        red[t] = p;
        __syncthreads();
        for (int s = 128; s > 0; s >>= 1) {
            if (t < s) red[t] += red[t + s];
            __syncthreads();
        }
        if (t == 0)
            ws[BIAS_OFF + col] = red[0] + ((col < NCLS) ? bc[cc] : bf[cc]);
    }
}

// ---------------- skinny GEMM core: C[M,40] (+=) A[M,2048] @ Bw[2048,40] ----
// Block: 1024 thr = 16 waves = 2 col-groups x 8 in-chunk K-splits over ONE
// shared 64-row x 64-k LDS tile (double-buffered). Bw is read via wave-uniform
// addresses (readfirstlane-forced) -> scalar s_loads, zero LDS/VMEM-per-lane
// cost. X: coalesced float4 global loads (lanes span k), transposed stride-65
// LDS store (conflict-free both ways). In-block LDS reduce over the 8 K-splits.
template<int NCHUNKS, bool FUSED>
__global__ __launch_bounds__(1024)
void skinny_gemm(const float* __restrict__ A,
                 const float* __restrict__ Bw,
                 float* __restrict__ Cacc,           // !FUSED: atomic target
                 const float* __restrict__ bias2,    // FUSED
                 float* __restrict__ outp)           // FUSED
{
    __shared__ float smem[SMEM_FLOATS];
    const int tid  = threadIdx.x;
    const int lane = tid & 63;
    const int wu   = __builtin_amdgcn_readfirstlane(tid >> 6);  // wave id 0..15
    const int cgu  = wu & 1;           // col-group: 20 cols
    const int ksu  = wu >> 1;          // in-chunk k-split 0..7
    const int ksub = ksu * 8;

    int m0, kbase;
    if (FUSED) { m0 = blockIdx.x * 64;        kbase = 0; }
    else       { m0 = (blockIdx.x >> 2) * 64; kbase = (blockIdx.x & 3) * (NCHUNKS * 64); }

    const int lrow = tid >> 4;         // 0..63 (4 rows per wave -> 256B segments)
    const int lkq  = tid & 15;         // 16 float4 per row = 64 k
    const float* aptr = A + (size_t)(m0 + lrow) * KD + kbase + 4 * lkq;

    v2f accv[10];
    #pragma unroll
    for (int j = 0; j < 10; ++j) accv[j] = (v2f){0.f, 0.f};

    // prologue: stage chunk 0 into buf 0
    float4 v = *(const float4*)(aptr);
    {
        float* xb = smem;
        xb[(4 * lkq + 0) * XS_STR + lrow] = v.x;
        xb[(4 * lkq + 1) * XS_STR + lrow] = v.y;
        xb[(4 * lkq + 2) * XS_STR + lrow] = v.z;
        xb[(4 * lkq + 3) * XS_STR + lrow] = v.w;
    }
    __syncthreads();

    for (int c = 0; c < NCHUNKS; ++c) {
        const int buf = c & 1;
        if (c + 1 < NCHUNKS)
            v = *(const float4*)(aptr + (c + 1) * 64);   // prefetch next chunk

        const float* xs   = smem + buf * XS_BUF;
        const float* brow = Bw + (size_t)(kbase + c * 64 + ksub) * NC2 + 20 * cgu;
        #pragma unroll 4
        for (int kk = 0; kk < 8; ++kk) {
            float x = xs[(ksub + kk) * XS_STR + lane];    // conflict-free gather
            v2f xx = {x, x};
            #pragma unroll
            for (int j2 = 0; j2 < 10; ++j2)               // 10 x v_pk_fma_f32
                accv[j2] = fma2(xx, *(const v2f*)(brow + kk * NC2 + 2 * j2),
                                accv[j2]);               // s_load_dwordx2 operand
        }

        if (c + 1 < NCHUNKS) {
            float* xb = smem + (buf ^ 1) * XS_BUF;
            xb[(4 * lkq + 0) * XS_STR + lrow] = v.x;
            xb[(4 * lkq + 1) * XS_STR + lrow] = v.y;
            xb[(4 * lkq + 2) * XS_STR + lrow] = v.z;
            xb[(4 * lkq + 3) * XS_STR + lrow] = v.w;
        }
        __syncthreads();
    }

    // in-block reduce over the 8 k-splits: Hacc[ks][row][c]  (aliases Xs, dead now)
    float* H = smem;
    #pragma unroll
    for (int j2 = 0; j2 < 10; ++j2) {
        H[ksu * HACC_WS + lane * HACC_STR + 20 * cgu + 2 * j2]     = accv[j2][0];
        H[ksu * HACC_WS + lane * HACC_STR + 20 * cgu + 2 * j2 + 1] = accv[j2][1];
    }
    __syncthreads();

    if (FUSED) {
        if (tid < 64) {
            float l[NC2];
            #pragma unroll
            for (int cc = 0; cc < NC2; ++cc) {
                float s = 0.f;
                #pragma unroll
                for (int ks = 0; ks < 8; ++ks)
                    s += H[ks * HACC_WS + tid * HACC_STR + cc];
                l[cc] = s + bias2[cc];
            }
            float mC = l[0];
            #pragma unroll
            for (int cc = 1; cc < NCLS; ++cc) mC = fmaxf(mC, l[cc]);
            float sC = 0.f;
            #pragma unroll
            for (int cc = 0; cc < NCLS; ++cc) sC += expf(l[cc] - mC);
            float mF = l[NCLS], mnF = l[NCLS];
            #pragma unroll
            for (int cc = NCLS + 1; cc < NC2; ++cc) {
                float vv = l[cc];
                mF = fmaxf(mF, vv);
                mnF = fminf(mnF, vv);
            }
            float sF = 0.f;
            #pragma unroll
            for (int cc = NCLS; cc < NC2; ++cc) sF += expf(l[cc] - mF);
            float pred  = 1.f / sC;                  // max softmax == exp(0)/sum
            float tau   = expf(mnF - mF) / sF;       // min softmax of flow head
            float scale = (pred >= tau + SMARG) ? pred : 0.f;
            float* op = outp + (size_t)(m0 + tid) * NCLS;
            #pragma unroll
            for (int cc = 0; cc < NCLS; ++cc)
                op[cc] = expf(l[cc] - mC) * scale;
        }
    } else {
        for (int idx = tid; idx < 64 * NC2; idx += 1024) {
            int row = idx / NC2, cc = idx % NC2;
            float s = 0.f;
            #pragma unroll
            for (int ks = 0; ks < 8; ++ks)
                s += H[ks * HACC_WS + row * HACC_STR + cc];
            atomicAdd(Cacc + (size_t)(m0 + row) * NC2 + cc, s);
        }
    }
}

extern "C" void kernel_launch(void* const* d_in, const int* in_sizes, int n_in,
                              void* d_out, int out_size, void* d_ws, size_t ws_size,
                              hipStream_t stream) {
    const float* X  = (const float*)d_in[0];
    const float* We = (const float*)d_in[1];
    const float* be = (const float*)d_in[2];
    const float* Wc = (const float*)d_in[3];
    const float* bc = (const float*)d_in[4];
    const float* Wf = (const float*)d_in[5];
    const float* bf = (const float*)d_in[6];
    float* out = (float*)d_out;
    float* ws  = (float*)d_ws;
    (void)in_sizes; (void)n_in; (void)out_size; (void)ws_size;

    // K0: pack Wcat, zero Weff, fold bias2
    k0_prep<<<dim3(360), dim3(256), 0, stream>>>(Wc, bc, Wf, bf, be, ws);
    // K1: Weff = We @ Wcat   (M=2048: 32 row-groups x 4 block-K-splits, atomic)
    skinny_gemm<8, false><<<dim3(128), dim3(1024), 0, stream>>>(
        We, ws + WCAT_OFF, ws + WEFF_OFF, nullptr, nullptr);
    // K2: out = softmax-threshold(X @ Weff + bias2)   (M=16384: 256 blocks)
    skinny_gemm<32, true><<<dim3(256), dim3(1024), 0, stream>>>(
        X, ws + WEFF_OFF, nullptr, ws + BIAS_OFF, out);
}